// Round 9
// baseline (212.937 us; speedup 1.0000x reference)
//
#include <hip/hip_runtime.h>

// HMM forward, log space. B=64 chains, D=128 steps, A=128 states.
// v_{t+1}[j] = log(sum_k exp(v_t[k]-Mn)*E[t][k][j]) + Mn + BC[b][t][j]
// E stored fp8 e4m3 scaled by 256 (all entries normal-range); -log256 folded
// into BC at prep. fwd: 64 blocks x 4 waves; wave w owns j in [32w,32w+32),
// lane halves k. E staged global->LDS via global_load_lds into 3 rotating
// 16KB buffers, DMA issued 2 steps ahead; one __syncthreads per step (its
// vmcnt(0) drain hits ~600-cycle-old DMAs -> residual ~0). No register
// prefetch (R5-R7: compiler refuses to keep it live, VGPR pinned at 84).

#define B_ 64
#define D_ 128
#define A_ 128
#define T_ 127
#define LN256 5.545177444479562f

// ws layout (4-byte units), ~6.24 MB
#define E8_UINTS (T_ * 4096)       // fp8 bytes, 16KB per t, fwd-consumption layout
#define BC_OFF E8_UINTS            // [b][t][j] fp32 (bern - LN256)
#define BC_SZ (B_ * T_ * A_)
#define LP_OFF (BC_OFF + BC_SZ)    // log_p_a1[j] fp32

#define AS1C(p) ((const __attribute__((address_space(1))) void*)(p))
#define AS3P(p) ((__attribute__((address_space(3))) void*)(p))

typedef float f2v __attribute__((ext_vector_type(2)));

// ---- fp8 e4m3 pack/unpack (hw builtins; manual fallback) ----
#if __has_builtin(__builtin_amdgcn_cvt_pk_f32_fp8)
template <int WORD>
__device__ __forceinline__ f2v unpk(unsigned int u) {
    return __builtin_amdgcn_cvt_pk_f32_fp8((int)u, WORD);
}
#else
__device__ __forceinline__ float fp8b_to_f32(unsigned int b) {
    unsigned int e = (b >> 3) & 15, m = b & 7;
    if (e) return __uint_as_float(((e + 120) << 23) | (m << 20));
    return (float)m * 0x1p-9f;  // our data is non-negative
}
template <int WORD>
__device__ __forceinline__ f2v unpk(unsigned int u) {
    unsigned int b0 = (u >> (WORD ? 16 : 0)) & 255;
    unsigned int b1 = (u >> (WORD ? 24 : 8)) & 255;
    f2v r; r.x = fp8b_to_f32(b0); r.y = fp8b_to_f32(b1);
    return r;
}
#endif

#if __has_builtin(__builtin_amdgcn_cvt_pk_fp8_f32)
__device__ __forceinline__ unsigned int pk4_fp8(float a, float b, float c, float d) {
    int v = __builtin_amdgcn_cvt_pk_fp8_f32(a, b, 0, false);
    v = __builtin_amdgcn_cvt_pk_fp8_f32(c, d, v, true);
    return (unsigned int)v;
}
#else
__device__ __forceinline__ unsigned int f32_to_fp8b(float f) {
    // f in [0, 448]
    if (f < 0.015625f) {
        int m = (int)rintf(f * 512.f);
        return (unsigned int)m;  // m<=8; m==8 -> 0x08 == 2^-6, correct
    }
    unsigned int fb = __float_as_uint(f);
    int ex = (int)((fb >> 23) & 255) - 127;
    unsigned int mant = (fb >> 20) & 7;
    unsigned int rem = fb & 0xFFFFFu;
    if (rem > 0x80000u || (rem == 0x80000u && (mant & 1))) mant++;
    int e8 = ex + 7;
    if (mant == 8) { mant = 0; e8++; }
    if (e8 > 15) return 0x7Eu;  // saturate to 448
    return ((unsigned int)e8 << 3) | mant;
}
__device__ __forceinline__ unsigned int pk4_fp8(float a, float b, float c, float d) {
    return f32_to_fp8b(a) | (f32_to_fp8b(b) << 8) |
           (f32_to_fp8b(c) << 16) | (f32_to_fp8b(d) << 24);
}
#endif

template <int CTRL>
__device__ __forceinline__ float dpp_mov_self(float x) {
    return __int_as_float(__builtin_amdgcn_update_dpp(
        __float_as_int(x), __float_as_int(x), CTRL, 0xF, 0xF, false));
}
template <int CTRL>
__device__ __forceinline__ float dpp_mov_zero(float x) {
    return __int_as_float(__builtin_amdgcn_update_dpp(
        0, __float_as_int(x), CTRL, 0xF, 0xF, true));
}
__device__ __forceinline__ float wave_max_partial(float x) {  // lane63 = wave max
    x = fmaxf(x, dpp_mov_self<0x111>(x));
    x = fmaxf(x, dpp_mov_self<0x112>(x));
    x = fmaxf(x, dpp_mov_self<0x114>(x));
    x = fmaxf(x, dpp_mov_self<0x118>(x));
    x = fmaxf(x, dpp_mov_self<0x142>(x));
    x = fmaxf(x, dpp_mov_self<0x143>(x));
    return x;
}
__device__ __forceinline__ float wave_max_bcast(float x) {
    return __int_as_float(__builtin_amdgcn_readlane(
        __float_as_int(wave_max_partial(x)), 63));
}
__device__ __forceinline__ float wave_sum_bcast(float x) {
    x += dpp_mov_zero<0x111>(x);
    x += dpp_mov_zero<0x112>(x);
    x += dpp_mov_zero<0x114>(x);
    x += dpp_mov_zero<0x118>(x);
    x += dpp_mov_zero<0x142>(x);
    x += dpp_mov_zero<0x143>(x);
    return __int_as_float(__builtin_amdgcn_readlane(__float_as_int(x), 63));
}

// ---------------- merged prep: 127 blocks x 256 ----------------
__global__ __launch_bounds__(256) void prep(const float* __restrict__ uT,
                                            const float* __restrict__ u1,
                                            const float* __restrict__ x,
                                            const float* __restrict__ lg,
                                            float* __restrict__ ws,
                                            float* __restrict__ out) {
    __shared__ float ul[128 * 128];   // 64KB
    const int t = blockIdx.x, tid = threadIdx.x;
    const float* u = uT + (size_t)t * A_ * A_;

    for (int i = tid; i < 4096; i += 256) {
        float4 v4 = ((const float4*)u)[i];
        *(float4*)&ul[(i >> 5) * 128 + (i & 31) * 4] = v4;
    }
    __syncthreads();

    // Z[r] = lse_j ul[r][j]; in-place ul -= Z (rotated index: no conflicts)
    if (tid < 128) {
        const int r = tid;
        float mx = -1e30f;
        for (int it = 0; it < 128; it++) mx = fmaxf(mx, ul[r * 128 + ((it + r) & 127)]);
        float s = 0.f;
        for (int it = 0; it < 128; it++) s += __expf(ul[r * 128 + ((it + r) & 127)] - mx);
        float Z = mx + __logf(s);
        for (int it = 0; it < 128; it++) ul[r * 128 + ((it + r) & 127)] -= Z;
    }
    __syncthreads();

    // E8 byte n (n=0..16383): n = c*4096 + h*2048 + w*512 + jl*16 + e
    //   k = 64h + 16c + e, j = 32w + jl, value = fp8(256 * exp(u[k][j]-Z[k]))
    unsigned int* Et = (unsigned int*)ws + (size_t)t * 4096;
    for (int it = 0; it < 16; it++) {
        int m = it * 256 + tid;            // uint index 0..4095
        int g = m >> 7;                    // c*8 + h*4 + w
        int c = g >> 3, h = (g >> 2) & 1, w = g & 3;
        int jl = (m >> 2) & 31;
        int k0 = 64 * h + 16 * c + 4 * (m & 3);
        int j = 32 * w + jl;
        float f0 = 256.f * __expf(ul[(k0 + 0) * 128 + j]);
        float f1 = 256.f * __expf(ul[(k0 + 1) * 128 + j]);
        float f2 = 256.f * __expf(ul[(k0 + 2) * 128 + j]);
        float f3 = 256.f * __expf(ul[(k0 + 3) * 128 + j]);
        Et[m] = pk4_fp8(f0, f1, f2, f3);
    }

    // BC[b][t][j] = bern(x[b][t+1], j) - LN256
    {
        int j = tid & 127, hb = tid >> 7;
        float lv = lg[(t + 1) * A_ + j];
        float sp = (lv > 0.f) ? (lv + log1pf(__expf(-lv))) : log1pf(__expf(lv));
        float g0 = -sp - LN256, g1 = lv - sp - LN256;
        float* BC = ws + BC_OFF;
        for (int b = hb * 32; b < hb * 32 + 32; b++) {
            float xv = x[b * D_ + t + 1];
            BC[((size_t)b * T_ + t) * A_ + j] = (xv != 0.f) ? g1 : g0;
        }
    }

    if (t == 0 && tid < 64) {   // log_softmax(u1) -> LP + output 1
        int lane = tid;
        float a = u1[lane], c = u1[lane + 64];
        float mx = wave_max_bcast(fmaxf(a, c));
        float s = wave_sum_bcast(__expf(a - mx) + __expf(c - mx));
        float lse = mx + __logf(s);
        ws[LP_OFF + lane] = a - lse;
        ws[LP_OFF + lane + 64] = c - lse;
        out[B_ * A_ + lane] = a - lse;
        out[B_ * A_ + lane + 64] = c - lse;
    }
}

// ---------------- main: 64 blocks x 256 (4 waves) ----------------
// Per-step: syncthreads -> ds_read E chunks (cur buf) -> issue DMA (t+2)
// -> fp8 unpack + fmac dots -> shfl combine -> log/exp -> publish ew/max.
#define STEP(T, BUFC, BUFN, P, DOISSUE)                                       \
    {                                                                         \
        __syncthreads();                                                      \
        uint4 ec0 = *(const uint4*)&Ebuf[BUFC][((0 + h) * 4 + w) * 512 + jl * 16]; \
        uint4 ec1 = *(const uint4*)&Ebuf[BUFC][((2 + h) * 4 + w) * 512 + jl * 16]; \
        uint4 ec2 = *(const uint4*)&Ebuf[BUFC][((4 + h) * 4 + w) * 512 + jl * 16]; \
        uint4 ec3 = *(const uint4*)&Ebuf[BUFC][((6 + h) * 4 + w) * 512 + jl * 16]; \
        if (DOISSUE) {                                                        \
            _Pragma("unroll") for (int i = 0; i < 4; i++)                     \
                __builtin_amdgcn_global_load_lds(                             \
                    AS1C(Eg + ((size_t)(T) + 2) * 16384 + (w * 4 + i) * 1024  \
                         + lane * 16),                                        \
                    AS3P(&Ebuf[BUFN][(w * 4 + i) * 1024]), 16, 0, 0);         \
        }                                                                     \
        float4 vm = *(const float4*)&vml[P][0];                               \
        float Mv = fmaxf(fmaxf(vm.x, vm.y), fmaxf(vm.z, vm.w));               \
        float a0 = 0, a1 = 0, a2 = 0, a3 = 0;                                 \
        _Pragma("unroll") for (int c = 0; c < 4; c++) {                       \
            uint4 ec = (c == 0) ? ec0 : (c == 1) ? ec1 : (c == 2) ? ec2 : ec3;\
            const float4* ewp = (const float4*)&ewf[P][64 * h + 16 * c];      \
            float4 w0 = ewp[0], w1 = ewp[1], w2 = ewp[2], w3 = ewp[3];        \
            f2v p0 = unpk<0>(ec.x), p1 = unpk<1>(ec.x);                       \
            a0 += p0.x * w0.x; a1 += p0.y * w0.y;                             \
            a2 += p1.x * w0.z; a3 += p1.y * w0.w;                             \
            f2v p2 = unpk<0>(ec.y), p3 = unpk<1>(ec.y);                       \
            a0 += p2.x * w1.x; a1 += p2.y * w1.y;                             \
            a2 += p3.x * w1.z; a3 += p3.y * w1.w;                             \
            f2v p4 = unpk<0>(ec.z), p5 = unpk<1>(ec.z);                       \
            a0 += p4.x * w2.x; a1 += p4.y * w2.y;                             \
            a2 += p5.x * w2.z; a3 += p5.y * w2.w;                             \
            f2v p6 = unpk<0>(ec.w), p7 = unpk<1>(ec.w);                       \
            a0 += p6.x * w3.x; a1 += p6.y * w3.y;                             \
            a2 += p7.x * w3.z; a3 += p7.y * w3.w;                             \
        }                                                                     \
        float S = (a0 + a1) + (a2 + a3);                                      \
        S += __shfl_xor(S, 32, 64);                                           \
        float vnew = __logf(S) + Mn + bcc;                                    \
        if (h == 0) ewf[P ^ 1][j] = __expf(vnew - Mv);                        \
        float wmx = wave_max_partial(vnew);                                   \
        if (lane == 63) vml[P ^ 1][w] = wmx;                                  \
        v = vnew;                                                             \
        Mn = Mv;                                                              \
        bcc = bcn;                                                            \
        if (DOISSUE) bcn = BCg[((T) + 2) * A_];                               \
    }

__global__ __launch_bounds__(256, 1) void fwd(const float* __restrict__ x,
                                              const float* __restrict__ lg,
                                              const float* __restrict__ ws,
                                              float* __restrict__ out) {
    __shared__ __align__(16) char Ebuf[3][16384];
    __shared__ __align__(16) float ewf[2][A_];
    __shared__ __align__(16) float vml[2][4];
    __shared__ float sums[4];
    const int b = blockIdx.x, tid = threadIdx.x;
    const int w = tid >> 6, lane = tid & 63;
    const int h = lane >> 5, jl = lane & 31;
    const int j = 32 * w + jl;

    const char* Eg = (const char*)ws;
    const float* BCg = ws + BC_OFF + (size_t)b * T_ * A_ + j;
    const float* LP = ws + LP_OFF;

    // prologue DMA: t=0 -> buf0, t=1 -> buf1
#pragma unroll
    for (int i = 0; i < 4; i++) {
        __builtin_amdgcn_global_load_lds(
            AS1C(Eg + (w * 4 + i) * 1024 + lane * 16),
            AS3P(&Ebuf[0][(w * 4 + i) * 1024]), 16, 0, 0);
        __builtin_amdgcn_global_load_lds(
            AS1C(Eg + 16384 + (w * 4 + i) * 1024 + lane * 16),
            AS3P(&Ebuf[1][(w * 4 + i) * 1024]), 16, 0, 0);
    }
    float bcc = BCg[0];
    float bcn = BCg[A_];

    // init: v_0[j] = log_p_a1[j] + bern(x[b][0], j)
    float ll = lg[j];
    float sp = (ll > 0.f) ? (ll + log1pf(__expf(-ll))) : log1pf(__expf(ll));
    float xv0 = x[b * D_];
    float v = LP[j] + ((xv0 != 0.f) ? (ll - sp) : (-sp));
    float wm0 = wave_max_partial(v);
    if (lane == 63) vml[0][w] = wm0;
    __syncthreads();
    float4 vm0 = *(const float4*)&vml[0][0];
    float Mn = fmaxf(fmaxf(vm0.x, vm0.y), fmaxf(vm0.z, vm0.w));
    if (h == 0) ewf[0][j] = __expf(v - Mn);

    for (int t = 0; t < 120; t += 6) {
        STEP(t + 0, 0, 2, 0, 1)
        STEP(t + 1, 1, 0, 1, 1)
        STEP(t + 2, 2, 1, 0, 1)
        STEP(t + 3, 0, 2, 1, 1)
        STEP(t + 4, 1, 0, 0, 1)
        STEP(t + 5, 2, 1, 1, 1)
    }
    STEP(120, 0, 2, 0, 1)
    STEP(121, 1, 0, 1, 1)
    STEP(122, 2, 1, 0, 1)
    STEP(123, 0, 2, 1, 1)
    STEP(124, 1, 0, 0, 1)
    STEP(125, 2, 1, 1, 0)
    STEP(126, 0, 2, 0, 0)

    // final: L = lse_j v_127[j]; step 126 wrote vml[1]
    __syncthreads();
    float4 vmf = *(const float4*)&vml[1][0];
    float Mf = fmaxf(fmaxf(vmf.x, vmf.y), fmaxf(vmf.z, vmf.w));
    float sw = wave_sum_bcast(__expf(v - Mf)) * 0.5f;  // halves duplicate j
    if (lane == 0) sums[w] = sw;
    __syncthreads();
    float L = Mf + __logf((sums[0] + sums[1]) + (sums[2] + sums[3]));
    if (tid < A_) out[b * A_ + tid] = L;
}

extern "C" void kernel_launch(void* const* d_in, const int* in_sizes, int n_in,
                              void* d_out, int out_size, void* d_ws, size_t ws_size,
                              hipStream_t stream) {
    const float* x = (const float*)d_in[0];    // [B,D]
    const float* u1 = (const float*)d_in[1];   // [1,1,1,A]
    const float* uT = (const float*)d_in[2];   // [D-1,A,A]
    const float* lg = (const float*)d_in[3];   // [1,D,1,A]
    float* ws = (float*)d_ws;                  // ~6.24 MB
    float* out = (float*)d_out;

    prep<<<dim3(T_), dim3(256), 0, stream>>>(uT, u1, x, lg, ws, out);
    fwd<<<dim3(B_), dim3(256), 0, stream>>>(x, lg, ws, out);
}

// Round 10
// 169.138 us; speedup vs baseline: 1.2590x; 1.2590x over previous
//
#include <hip/hip_runtime.h>

// HMM forward, log space. B=64 chains, D=128 steps, A=128 states.
// Prob-domain recursion with lagged renormalization (NO log/exp in-loop):
//   w_{t+1}[j] = G[b][t][j] * sum_k wHat_t[k] E_t[k][j],  wHat = w / maxW_lag
//   v_t = beta_t + log w_t;  beta accumulates dangling logf's off-path.
// E fp16 pair-packed (R6 layout), G = exp(bern) fp32, both prefetched one
// step ahead via ASM VOLATILE global loads + tied-operand s_waitcnt vmcnt(9)
// (never 0) -- compiler cannot sink or drain them (R5-R9: every compiler-
// managed variant either sank the prefetch or drained at barriers).
// fwd: 64 blocks x 4 waves; wave wv owns j in [32wv,32wv+32), lane halves k;
// ew exchange via fp16 LDS + raw s_barrier (lgkmcnt-only drain).

#define B_ 64
#define D_ 128
#define A_ 128
#define T_ 127

// ws layout (4-byte units), ~8.3 MB
#define E16_UINTS (T_ * 8192)      // fp16 pairs: byte = t*32768+q*4096+h*2048+wv*512+jl*16
#define G_OFF E16_UINTS            // [b][t][j] fp32 = exp(bern(x[b][t+1], j))
#define G_SZ (B_ * T_ * A_)
#define LP_OFF (G_OFF + G_SZ)      // log_p_a1[j] fp32

typedef _Float16 h2 __attribute__((ext_vector_type(2)));
typedef unsigned int u32x4 __attribute__((ext_vector_type(4)));

__device__ __forceinline__ int packrtz(float a, float b) {
    auto p = __builtin_amdgcn_cvt_pkrtz(a, b); // low=a, high=b
    return __builtin_bit_cast(int, p);
}
__device__ __forceinline__ float dot2acc(unsigned int e, unsigned int s, float acc) {
    return __builtin_amdgcn_fdot2(__builtin_bit_cast(h2, e),
                                  __builtin_bit_cast(h2, s), acc, false);
}

template <int CTRL>
__device__ __forceinline__ float dpp_mov_self(float x) {
    return __int_as_float(__builtin_amdgcn_update_dpp(
        __float_as_int(x), __float_as_int(x), CTRL, 0xF, 0xF, false));
}
template <int CTRL>
__device__ __forceinline__ float dpp_mov_zero(float x) {
    return __int_as_float(__builtin_amdgcn_update_dpp(
        0, __float_as_int(x), CTRL, 0xF, 0xF, true));
}
__device__ __forceinline__ float wave_max_partial(float x) { // lane63 = wave max
    x = fmaxf(x, dpp_mov_self<0x111>(x));
    x = fmaxf(x, dpp_mov_self<0x112>(x));
    x = fmaxf(x, dpp_mov_self<0x114>(x));
    x = fmaxf(x, dpp_mov_self<0x118>(x));
    x = fmaxf(x, dpp_mov_self<0x142>(x));
    x = fmaxf(x, dpp_mov_self<0x143>(x));
    return x;
}
__device__ __forceinline__ float wave_max_bcast(float x) {
    return __int_as_float(__builtin_amdgcn_readlane(
        __float_as_int(wave_max_partial(x)), 63));
}
__device__ __forceinline__ float wave_sum_bcast(float x) {
    x += dpp_mov_zero<0x111>(x);
    x += dpp_mov_zero<0x112>(x);
    x += dpp_mov_zero<0x114>(x);
    x += dpp_mov_zero<0x118>(x);
    x += dpp_mov_zero<0x142>(x);
    x += dpp_mov_zero<0x143>(x);
    return __int_as_float(__builtin_amdgcn_readlane(__float_as_int(x), 63));
}

// ---------------- merged prep: 127 blocks x 256, LDS-staged ----------------
__global__ __launch_bounds__(256) void prep(const float* __restrict__ uT,
                                            const float* __restrict__ u1,
                                            const float* __restrict__ x,
                                            const float* __restrict__ lg,
                                            float* __restrict__ ws,
                                            float* __restrict__ out) {
    __shared__ float ul[128 * 128];   // 64KB
    const int t = blockIdx.x, tid = threadIdx.x;
    const float* u = uT + (size_t)t * A_ * A_;

    for (int i = tid; i < 4096; i += 256) {
        float4 v4 = ((const float4*)u)[i];
        *(float4*)&ul[(i >> 5) * 128 + (i & 31) * 4] = v4;
    }
    __syncthreads();

    // Z[r] = lse_j ul[r][j]; in-place ul -= Z (rotated index: conflict-free)
    if (tid < 128) {
        const int r = tid;
        float mx = -1e30f;
        for (int it = 0; it < 128; it++) mx = fmaxf(mx, ul[r * 128 + ((it + r) & 127)]);
        float s = 0.f;
        for (int it = 0; it < 128; it++) s += __expf(ul[r * 128 + ((it + r) & 127)] - mx);
        float Z = mx + __logf(s);
        for (int it = 0; it < 128; it++) ul[r * 128 + ((it + r) & 127)] -= Z;
    }
    __syncthreads();

    // E16 uint a: a = q*1024 + h*512 + w*128 + jl*4 + c (q<8);
    // pair (e(2i,j), e(2i+1,j)), i = 32h+4q+c, j = 32w+jl
    unsigned int* Et = (unsigned int*)ws + (size_t)t * 8192;
    for (int it = 0; it < 32; it++) {
        int a = it * 256 + tid;
        int c = a & 3, jl = (a >> 2) & 31, w = (a >> 7) & 3;
        int h = (a >> 9) & 1, q = a >> 10;
        int i = 32 * h + 4 * q + c;
        int j = 32 * w + jl;
        float e0 = __expf(ul[(2 * i) * 128 + j]);
        float e1 = __expf(ul[(2 * i + 1) * 128 + j]);
        Et[a] = (unsigned int)packrtz(e0, e1);
    }

    // G[b][t][j] = exp(bern(x[b][t+1], j))
    {
        int j = tid & 127, hb = tid >> 7;
        float lv = lg[(t + 1) * A_ + j];
        float sp = (lv > 0.f) ? (lv + log1pf(__expf(-lv))) : log1pf(__expf(lv));
        float G0 = __expf(-sp), G1 = __expf(lv - sp);
        float* G = ws + G_OFF;
        for (int b = hb * 32; b < hb * 32 + 32; b++) {
            float xv = x[b * D_ + t + 1];
            G[((size_t)b * T_ + t) * A_ + j] = (xv != 0.f) ? G1 : G0;
        }
    }

    if (t == 0 && tid < 64) {   // log_softmax(u1) -> LP + output 1
        int lane = tid;
        float a = u1[lane], c = u1[lane + 64];
        float mx = wave_max_bcast(fmaxf(a, c));
        float s = wave_sum_bcast(__expf(a - mx) + __expf(c - mx));
        float lse = mx + __logf(s);
        ws[LP_OFF + lane] = a - lse;
        ws[LP_OFF + lane + 64] = c - lse;
        out[B_ * A_ + lane] = a - lse;
        out[B_ * A_ + lane + 64] = c - lse;
    }
}

// ---------------- main: 64 blocks x 256 (4 waves), raw barriers ----------------
#define BARRIER() asm volatile("s_waitcnt lgkmcnt(0)\n\ts_barrier" ::: "memory")

#define ISSUE(EN, GN, TT)                                                     \
    {                                                                         \
        unsigned long long ab = Ebase + (unsigned long long)(TT) * 32768ull;  \
        _Pragma("unroll") for (int q = 0; q < 8; q++)                         \
            asm volatile("global_load_dwordx4 %0, %1, off"                    \
                         : "=v"(EN[q])                                        \
                         : "v"(ab + (unsigned long long)(q * 4096)));         \
        asm volatile("global_load_dword %0, %1, off"                          \
                     : "=v"(GN)                                               \
                     : "v"(Gbase + (unsigned long long)(TT) * 512ull));       \
    }

#define WAITON(EC, GC, CNT)                                                   \
    asm volatile("s_waitcnt vmcnt(" #CNT ")"                                  \
                 : "+v"(EC[0]), "+v"(EC[1]), "+v"(EC[2]), "+v"(EC[3]),        \
                   "+v"(EC[4]), "+v"(EC[5]), "+v"(EC[6]), "+v"(EC[7]),        \
                   "+v"(GC));

#define BODY(T, EC, GC)                                                       \
    {                                                                         \
        const int p = (T) & 1, np = p ^ 1;                                    \
        float4 vm4 = *(const float4*)&vml[p][0];                              \
        float maxW = fmaxf(fmaxf(vm4.x, vm4.y), fmaxf(vm4.z, vm4.w));         \
        float srec = 1.0f / maxW;                                             \
        beta += __logf(mprev);   /* dangling, off critical path */            \
        mprev = maxW;                                                         \
        const uint4* ewp = (const uint4*)&ewl[p][0] + h * 8;                  \
        float a0 = 0, a1 = 0, a2 = 0, a3 = 0;                                 \
        _Pragma("unroll") for (int q = 0; q < 8; q++) {                       \
            uint4 ew4 = ewp[q];                                               \
            a0 = dot2acc(EC[q].x, ew4.x, a0);                                 \
            a1 = dot2acc(EC[q].y, ew4.y, a1);                                 \
            a2 = dot2acc(EC[q].z, ew4.z, a2);                                 \
            a3 = dot2acc(EC[q].w, ew4.w, a3);                                 \
        }                                                                     \
        float S = (a0 + a1) + (a2 + a3);                                      \
        S += __shfl_xor(S, 32, 64);                                           \
        float W = S * GC;                                                     \
        if (h == 0) ewl[np][j] = (_Float16)(W * srec);                        \
        float wm = wave_max_partial(W);  /* dangling */                       \
        if (lane == 63) vml[np][wv] = wm;                                     \
        Wlast = W;                                                            \
        BARRIER();                                                            \
    }

#define STEPP(T, EC, EN, GC, GN)                                              \
    {                                                                         \
        ISSUE(EN, GN, (T) + 1)                                                \
        WAITON(EC, GC, 9)                                                     \
        BODY(T, EC, GC)                                                       \
    }
#define STEPL(T, EC, GC)                                                      \
    {                                                                         \
        WAITON(EC, GC, 0)                                                     \
        BODY(T, EC, GC)                                                       \
    }

__global__ __launch_bounds__(256, 1) void fwd(const float* __restrict__ x,
                                              const float* __restrict__ lg,
                                              const float* __restrict__ ws,
                                              float* __restrict__ out) {
    __shared__ __align__(16) _Float16 ewl[2][A_];
    __shared__ __align__(16) float vml[2][4];
    __shared__ float sums[4];
    const int b = blockIdx.x, tid = threadIdx.x;
    const int wv = tid >> 6, lane = tid & 63;
    const int h = lane >> 5, jl = lane & 31;
    const int j = 32 * wv + jl;

    const unsigned long long Ebase =
        (unsigned long long)ws + (unsigned long long)(h * 2048 + wv * 512 + jl * 16);
    const unsigned long long Gbase =
        (unsigned long long)(ws + G_OFF + (size_t)b * T_ * A_ + j);
    const float* LP = ws + LP_OFF;

    u32x4 EA[8], EB[8];
    float gA, gB;
    ISSUE(EA, gA, 0)   // preload t=0 batch (9 vm ops)

    // init: v_0[j] = log_p_a1[j] + bern(x[b][0], j)
    float ll = lg[j];
    float sp = (ll > 0.f) ? (ll + log1pf(__expf(-ll))) : log1pf(__expf(ll));
    float xv0 = x[b * D_];
    float v0 = LP[j] + ((xv0 != 0.f) ? (ll - sp) : (-sp));
    float wm0 = wave_max_partial(v0);
    if (lane == 63) vml[0][wv] = wm0;
    BARRIER();
    float4 vmi = *(const float4*)&vml[0][0];
    float M0 = fmaxf(fmaxf(vmi.x, vmi.y), fmaxf(vmi.z, vmi.w));
    float w0 = __expf(v0 - M0);              // wHat_0 <= 1
    if (h == 0) ewl[0][j] = (_Float16)w0;
    float wmW = wave_max_partial(w0);        // vml[0] := wave maxes of w_0
    if (lane == 63) vml[0][wv] = wmW;
    BARRIER();

    float beta = M0, mprev = 1.0f, Wlast = 0.f;

    for (int t = 0; t < 126; t += 2) {       // steps 0..125
        STEPP(t + 0, EA, EB, gA, gB)
        STEPP(t + 1, EB, EA, gB, gA)
    }
    STEPL(126, EA, gA)

    // final: L = beta + log(sum_j w_127[j])   (halves duplicate each j)
    float sw = wave_sum_bcast(Wlast) * 0.5f;
    if (lane == 0) sums[wv] = sw;
    __syncthreads();
    float tot = (sums[0] + sums[1]) + (sums[2] + sums[3]);
    float L = beta + __logf(tot);
    if (tid < A_) out[b * A_ + tid] = L;
}

extern "C" void kernel_launch(void* const* d_in, const int* in_sizes, int n_in,
                              void* d_out, int out_size, void* d_ws, size_t ws_size,
                              hipStream_t stream) {
    const float* x = (const float*)d_in[0];    // [B,D]
    const float* u1 = (const float*)d_in[1];   // [1,1,1,A]
    const float* uT = (const float*)d_in[2];   // [D-1,A,A]
    const float* lg = (const float*)d_in[3];   // [1,D,1,A]
    float* ws = (float*)d_ws;                  // ~8.3 MB
    float* out = (float*)d_out;

    prep<<<dim3(T_), dim3(256), 0, stream>>>(uT, u1, x, lg, ws, out);
    fwd<<<dim3(B_), dim3(256), 0, stream>>>(x, lg, ws, out);
}

// Round 11
// 162.753 us; speedup vs baseline: 1.3083x; 1.0392x over previous
//
#include <hip/hip_runtime.h>

// HMM forward, log space. B=64 chains, D=128 steps, A=128 states.
// Prob-domain recursion, lagged renormalization (no log/exp in loop):
//   W_{t+1}[j] = G[b][t][j] * sum_k wHat_t[k] E_t[k][j],  wHat = W/maxW_lag
// E fp8 e4m3 scaled x256 (2.08 MB); G-table replaced by GP[t][j] pair table
// (130 KB, /256 folded in) selected by x[b][t+1] from LDS -> working set
// 2.2 MB fits per-XCD L2 (R10 lesson: 8.3 MB thrashed L2 -> step was
// L2/L3-delivery-bound, 32KB/step/CU). Loads are ASM VOLATILE + tied-operand
// s_waitcnt vmcnt(10), 3-buffer 2-step lead. 4 waves, fp16 ew exchange,
// raw s_barrier (lgkmcnt-only).

#define B_ 64
#define D_ 128
#define A_ 128
#define T_ 127

// ws layout (float units), ~2.2 MB
#define E8_FLOATS (T_ * 4096)          // fp8: byte = t*16384+q*4096+h*2048+wv*512+jl*16+e
#define GP_OFF E8_FLOATS               // [t][j] float2 {exp(-sp)/256, exp(lv-sp)/256}
#define GP_SZ (T_ * A_ * 2)
#define LP_OFF (GP_OFF + GP_SZ)        // log_p_a1[j] fp32

typedef _Float16 h2 __attribute__((ext_vector_type(2)));
typedef unsigned int u32x4 __attribute__((ext_vector_type(4)));
typedef float f2v __attribute__((ext_vector_type(2)));

__device__ __forceinline__ int packrtz(float a, float b) {
    auto p = __builtin_amdgcn_cvt_pkrtz(a, b); // low=a, high=b
    return __builtin_bit_cast(int, p);
}
__device__ __forceinline__ float dot2acc(int e, unsigned int s, float acc) {
    return __builtin_amdgcn_fdot2(__builtin_bit_cast(h2, e),
                                  __builtin_bit_cast(h2, s), acc, false);
}

// fp8 e4m3 (proven R9)
template <int WORD>
__device__ __forceinline__ f2v unpk(unsigned int u) {
    return __builtin_amdgcn_cvt_pk_f32_fp8((int)u, WORD);
}
__device__ __forceinline__ unsigned int pk4_fp8(float a, float b, float c, float d) {
    int v = __builtin_amdgcn_cvt_pk_fp8_f32(a, b, 0, false);
    v = __builtin_amdgcn_cvt_pk_fp8_f32(c, d, v, true);
    return (unsigned int)v;
}

template <int CTRL>
__device__ __forceinline__ float dpp_mov_self(float x) {
    return __int_as_float(__builtin_amdgcn_update_dpp(
        __float_as_int(x), __float_as_int(x), CTRL, 0xF, 0xF, false));
}
template <int CTRL>
__device__ __forceinline__ float dpp_mov_zero(float x) {
    return __int_as_float(__builtin_amdgcn_update_dpp(
        0, __float_as_int(x), CTRL, 0xF, 0xF, true));
}
__device__ __forceinline__ float wave_max_partial(float x) { // lane63 = wave max
    x = fmaxf(x, dpp_mov_self<0x111>(x));
    x = fmaxf(x, dpp_mov_self<0x112>(x));
    x = fmaxf(x, dpp_mov_self<0x114>(x));
    x = fmaxf(x, dpp_mov_self<0x118>(x));
    x = fmaxf(x, dpp_mov_self<0x142>(x));
    x = fmaxf(x, dpp_mov_self<0x143>(x));
    return x;
}
__device__ __forceinline__ float wave_max_bcast(float x) {
    return __int_as_float(__builtin_amdgcn_readlane(
        __float_as_int(wave_max_partial(x)), 63));
}
__device__ __forceinline__ float wave_sum_bcast(float x) {
    x += dpp_mov_zero<0x111>(x);
    x += dpp_mov_zero<0x112>(x);
    x += dpp_mov_zero<0x114>(x);
    x += dpp_mov_zero<0x118>(x);
    x += dpp_mov_zero<0x142>(x);
    x += dpp_mov_zero<0x143>(x);
    return __int_as_float(__builtin_amdgcn_readlane(__float_as_int(x), 63));
}

// ---------------- merged prep: 127 blocks x 256, LDS-staged ----------------
__global__ __launch_bounds__(256) void prep(const float* __restrict__ uT,
                                            const float* __restrict__ u1,
                                            const float* __restrict__ x,
                                            const float* __restrict__ lg,
                                            float* __restrict__ ws,
                                            float* __restrict__ out) {
    __shared__ float ul[128 * 128];   // 64KB
    const int t = blockIdx.x, tid = threadIdx.x;
    const float* u = uT + (size_t)t * A_ * A_;

    for (int i = tid; i < 4096; i += 256) {
        float4 v4 = ((const float4*)u)[i];
        *(float4*)&ul[(i >> 5) * 128 + (i & 31) * 4] = v4;
    }
    __syncthreads();

    // Z[r] = lse_j ul[r][j]; in-place ul -= Z (rotated index: conflict-free)
    if (tid < 128) {
        const int r = tid;
        float mx = -1e30f;
        for (int it = 0; it < 128; it++) mx = fmaxf(mx, ul[r * 128 + ((it + r) & 127)]);
        float s = 0.f;
        for (int it = 0; it < 128; it++) s += __expf(ul[r * 128 + ((it + r) & 127)] - mx);
        float Z = mx + __logf(s);
        for (int it = 0; it < 128; it++) ul[r * 128 + ((it + r) & 127)] -= Z;
    }
    __syncthreads();

    // E8 uint m: m = q*1024 + h*512 + wv*128 + jl*4 + c; bytes = k0..k0+3
    // k0 = 64h+16q+4c, j = 32wv+jl, val = fp8(256*exp(u[k][j]-Z[k]))
    unsigned int* Et = (unsigned int*)ws + (size_t)t * 4096;
    for (int it = 0; it < 16; it++) {
        int m = it * 256 + tid;
        int c = m & 3, jl = (m >> 2) & 31, wv = (m >> 7) & 3;
        int h = (m >> 9) & 1, q = (m >> 10) & 3;
        int k0 = 64 * h + 16 * q + 4 * c;
        int j = 32 * wv + jl;
        float f0 = 256.f * __expf(ul[(k0 + 0) * 128 + j]);
        float f1 = 256.f * __expf(ul[(k0 + 1) * 128 + j]);
        float f2 = 256.f * __expf(ul[(k0 + 2) * 128 + j]);
        float f3 = 256.f * __expf(ul[(k0 + 3) * 128 + j]);
        Et[m] = pk4_fp8(f0, f1, f2, f3);
    }

    // GP[t][j] = {exp(-sp)/256, exp(lv-sp)/256}  (bern at time t+1)
    if (tid < 128) {
        int j = tid;
        float lv = lg[(t + 1) * A_ + j];
        float sp = (lv > 0.f) ? (lv + log1pf(__expf(-lv))) : log1pf(__expf(lv));
        float2 gp = make_float2(__expf(-sp) * 0.00390625f,
                                __expf(lv - sp) * 0.00390625f);
        *(float2*)&ws[GP_OFF + ((size_t)t * A_ + j) * 2] = gp;
    }

    if (t == 0 && tid < 64) {   // log_softmax(u1) -> LP + output 1
        int lane = tid;
        float a = u1[lane], c = u1[lane + 64];
        float mx = wave_max_bcast(fmaxf(a, c));
        float s = wave_sum_bcast(__expf(a - mx) + __expf(c - mx));
        float lse = mx + __logf(s);
        ws[LP_OFF + lane] = a - lse;
        ws[LP_OFF + lane + 64] = c - lse;
        out[B_ * A_ + lane] = a - lse;
        out[B_ * A_ + lane + 64] = c - lse;
    }
}

// ---------------- main: 64 blocks x 256 (4 waves), raw barriers ----------------
#define BARRIER() asm volatile("s_waitcnt lgkmcnt(0)\n\ts_barrier" ::: "memory")

#define ISSUE(EN, GN, TT)                                                     \
    {                                                                         \
        unsigned long long ab = Ebase + (unsigned long long)(TT) * 16384ull;  \
        _Pragma("unroll") for (int q = 0; q < 4; q++)                         \
            asm volatile("global_load_dwordx4 %0, %1, off"                    \
                         : "=v"(EN[q])                                        \
                         : "v"(ab + (unsigned long long)(q * 4096)));         \
        asm volatile("global_load_dwordx2 %0, %1, off"                        \
                     : "=v"(GN)                                               \
                     : "v"(Gbase + (unsigned long long)(TT) * 1024ull));      \
    }

#define WAITON(EC, GC, CNT)                                                   \
    asm volatile("s_waitcnt vmcnt(" #CNT ")"                                  \
                 : "+v"(EC[0]), "+v"(EC[1]), "+v"(EC[2]), "+v"(EC[3]),        \
                   "+v"(GC));

#define BODY(T, EC, GC)                                                       \
    {                                                                         \
        const int p = (T) & 1, np = p ^ 1;                                    \
        float4 vm4 = *(const float4*)&vml[p][0];                              \
        float maxW = fmaxf(fmaxf(vm4.x, vm4.y), fmaxf(vm4.z, vm4.w));         \
        float srec = 1.0f / maxW;                                             \
        beta += __logf(mprev);   /* dangling, off critical path */            \
        mprev = maxW;                                                         \
        float xv = xl[(T) + 1];                                               \
        uint4 ew4[8];                                                         \
        const uint4* ewp = (const uint4*)&ewl[p][0] + h * 8;                  \
        _Pragma("unroll") for (int q = 0; q < 8; q++) ew4[q] = ewp[q];        \
        float a0 = 0, a1 = 0, a2 = 0, a3 = 0;                                 \
        _Pragma("unroll") for (int q = 0; q < 4; q++) {                       \
            _Pragma("unroll") for (int m = 0; m < 4; m++) {                   \
                unsigned int eu = EC[q][m];                                   \
                f2v lo = unpk<0>(eu), hi = unpk<1>(eu);                       \
                const int i0 = 8 * q + 2 * m, i1 = i0 + 1;                    \
                unsigned int w0 = ew4[i0 >> 2][i0 & 3];                       \
                unsigned int w1 = ew4[i1 >> 2][i1 & 3];                       \
                a0 = dot2acc(packrtz(lo.x, lo.y), w0, a0);                    \
                a1 = dot2acc(packrtz(hi.x, hi.y), w1, a1);                    \
            }                                                                 \
        }                                                                     \
        float S = a0 + a1 + a2 + a3;                                          \
        S += __shfl_xor(S, 32, 64);                                           \
        float gsel = (xv != 0.f) ? GC.y : GC.x;                               \
        float W = S * gsel;                                                   \
        if (h == 0) ewl[np][j] = (_Float16)(W * srec);                        \
        float wm = wave_max_partial(W);  /* dangling */                       \
        if (lane == 63) vml[np][wv] = wm;                                     \
        Wlast = W;                                                            \
        BARRIER();                                                            \
    }

#define STEPP(T, EC, EN, GC, GN)                                              \
    {                                                                         \
        ISSUE(EN, GN, (T) + 2)                                                \
        WAITON(EC, GC, 10)                                                    \
        BODY(T, EC, GC)                                                       \
    }

__global__ __launch_bounds__(256, 1) void fwd(const float* __restrict__ x,
                                              const float* __restrict__ lg,
                                              const float* __restrict__ ws,
                                              float* __restrict__ out) {
    __shared__ __align__(16) _Float16 ewl[2][A_];
    __shared__ __align__(16) float vml[2][4];
    __shared__ float xl[D_];
    __shared__ float sums[4];
    const int b = blockIdx.x, tid = threadIdx.x;
    const int wv = tid >> 6, lane = tid & 63;
    const int h = lane >> 5, jl = lane & 31;
    const int j = 32 * wv + jl;

    const unsigned long long Ebase =
        (unsigned long long)ws + (unsigned long long)(h * 2048 + wv * 512 + jl * 16);
    const unsigned long long Gbase =
        (unsigned long long)(ws + GP_OFF) + (unsigned long long)(j * 8);
    const float* LP = ws + LP_OFF;

    u32x4 EA[4], EB[4], EC_[4];
    f2v gA, gB, gC;
    ISSUE(EA, gA, 0)
    ISSUE(EB, gB, 1)

    if (tid < D_) xl[tid] = x[b * D_ + tid];

    // init: v_0[j] = log_p_a1[j] + bern(x[b][0], j)
    float ll = lg[j];
    float sp = (ll > 0.f) ? (ll + log1pf(__expf(-ll))) : log1pf(__expf(ll));
    float xv0 = x[b * D_];
    float v0 = LP[j] + ((xv0 != 0.f) ? (ll - sp) : (-sp));
    float wm0 = wave_max_partial(v0);
    if (lane == 63) vml[0][wv] = wm0;
    BARRIER();
    float4 vmi = *(const float4*)&vml[0][0];
    float M0 = fmaxf(fmaxf(vmi.x, vmi.y), fmaxf(vmi.z, vmi.w));
    float w0 = __expf(v0 - M0);              // wHat_0 <= 1
    if (h == 0) ewl[0][j] = (_Float16)w0;
    float wmW = wave_max_partial(w0);        // vml[0] := wave maxes of w_0
    if (lane == 63) vml[0][wv] = wmW;
    BARRIER();

    float beta = M0, mprev = 1.0f, Wlast = 0.f;

    for (int t = 0; t < 123; t += 3) {       // steps 0..122, issue 2..124
        STEPP(t + 0, EA, EC_, gA, gC)
        STEPP(t + 1, EB, EA, gB, gA)
        STEPP(t + 2, EC_, EB, gC, gB)
    }
    STEPP(123, EA, EC_, gA, gC)              // issue 125 -> C
    STEPP(124, EB, EA, gB, gA)               // issue 126 -> A
    {   // t=125: consume C; outstanding {125(C),126(A)} -> wait 5
        WAITON(EC_, gC, 5)
        BODY(125, EC_, gC)
    }
    {   // t=126: consume A
        WAITON(EA, gA, 0)
        BODY(126, EA, gA)
    }

    // final: L = beta + log(mprev) ... handled by lse of W_127 via beta chain
    float sw = wave_sum_bcast(Wlast) * 0.5f;  // halves duplicate each j
    if (lane == 0) sums[wv] = sw;
    __syncthreads();
    float tot = (sums[0] + sums[1]) + (sums[2] + sums[3]);
    float L = beta + __logf(mprev) + __logf(tot) - __logf(mprev); // = beta + log tot
    L = beta + __logf(tot);
    if (tid < A_) out[b * A_ + tid] = L;
}

extern "C" void kernel_launch(void* const* d_in, const int* in_sizes, int n_in,
                              void* d_out, int out_size, void* d_ws, size_t ws_size,
                              hipStream_t stream) {
    const float* x = (const float*)d_in[0];    // [B,D]
    const float* u1 = (const float*)d_in[1];   // [1,1,1,A]
    const float* uT = (const float*)d_in[2];   // [D-1,A,A]
    const float* lg = (const float*)d_in[3];   // [1,D,1,A]
    float* ws = (float*)d_ws;                  // ~2.2 MB
    float* out = (float*)d_out;

    prep<<<dim3(T_), dim3(256), 0, stream>>>(uT, u1, x, lg, ws, out);
    fwd<<<dim3(B_), dim3(256), 0, stream>>>(x, lg, ws, out);
}